// Round 12
// baseline (203.505 us; speedup 1.0000x reference)
//
#include <hip/hip_runtime.h>
#include <math.h>

#define L 16384
#define H 128
#define P 256
#define CL 32
#define NCH (L/CL)   // 512 chunks
#define GS 16        // chunks per group
#define NG (NCH/GS)  // 32 groups
#define KDIM 512     // out-GEMM K = [x2re | x2im]
#define NBU 512      // bu-GEMM N  = [BuRe | BuIm]

typedef __attribute__((ext_vector_type(8))) short short8;   // 8 bf16
typedef __attribute__((ext_vector_type(4))) float f32x4;

__device__ inline unsigned short f2bf(float f){          // fp32 -> bf16 RNE
  union { float f; unsigned u; } v; v.f = f;
  unsigned u = v.u;
  u += 0x7fffu + ((u >> 16) & 1u);
  return (unsigned short)(u >> 16);
}
__device__ inline float bf2f(unsigned short s){
  union { unsigned u; float f; } v; v.u = ((unsigned)s) << 16;
  return v.f;
}

struct Params { float M11,M12,M21,M22,s1,s2; };

__device__ inline Params get_params(const float* A_diag, const float* steps, int p){
  float A = A_diag[p]; A = A > 0.f ? A : 0.f;          // relu
  float dt = 1.f/(1.f + expf(-steps[p]));              // sigmoid
  float schur = 1.f/(1.f + dt*dt*A);
  Params q;
  q.M11 = 1.f - dt*dt*A*schur;
  q.M12 = -dt*A*schur;
  q.M21 = dt*schur;
  q.M22 = schur;
  q.s1 = q.M11*dt;
  q.s2 = q.M21*dt;
  return q;
}

// ---- K0: prep — weight swizzles (bf16) + zero group counters ----------------
// 256 blocks x 512: gid 0..65535 -> BW swizzle, 65536..131071 -> C swizzle.
__global__ __launch_bounds__(512) void prep_w(const float* __restrict__ B,
                                              const float* __restrict__ Cw,
                                              unsigned short* __restrict__ BWswz,
                                              unsigned short* __restrict__ Bswz,
                                              unsigned* __restrict__ cnt){
  int gid = blockIdx.x*512 + threadIdx.x;
  if (gid < H*NBU){                            // BW: k=h 0..127, n 0..511
    int k = gid >> 9, n = gid & 511;
    int p = n & 255, c2 = n >> 8;
    float v = B[((size_t)p*H + k)*2 + c2];
    BWswz[((size_t)(k>>3)*NBU + n)*8 + (k&7)] = f2bf(v);
  } else {
    int g2 = gid - H*NBU;                      // C: k 0..511, n=h 0..127
    int k = g2 >> 7, n = g2 & 127;
    float v = (k < P) ? Cw[((size_t)n*P + k)*2]
                      : -Cw[((size_t)n*P + (k-P))*2 + 1];
    Bswz[((size_t)(k>>3)*H + n)*8 + (k&7)] = f2bf(v);
  }
  if (gid < NG) cnt[gid] = 0u;                 // zero completion counters every call
}

// ---- shared helper: MFMA one chunk of Bu into LDS (bf16), A direct from fp32 in ----
__device__ inline void chunk_bu_to_lds(int c, const float* __restrict__ in,
                                       const short* __restrict__ BWswz,
                                       unsigned short (*sBu)[NBU+8]){
  int tid = threadIdx.x;
  int lane = tid & 63, w = tid >> 6;
  int ml = lane & 15, quad = lane >> 4;
  int mt = w & 1, ng = w >> 1;
  int lm0 = mt*16;
  const float* aptr = in + (size_t)(c*CL + lm0 + ml)*H + quad*8;
  short8 av[4];
  #pragma unroll
  for (int ks=0; ks<4; ks++){
    float4 f0 = *(const float4*)(aptr + ks*32);
    float4 f1 = *(const float4*)(aptr + ks*32 + 4);
    union { short8 s; unsigned short u[8]; } o;
    o.u[0]=f2bf(f0.x); o.u[1]=f2bf(f0.y); o.u[2]=f2bf(f0.z); o.u[3]=f2bf(f0.w);
    o.u[4]=f2bf(f1.x); o.u[5]=f2bf(f1.y); o.u[6]=f2bf(f1.z); o.u[7]=f2bf(f1.w);
    av[ks] = o.s;
  }
  f32x4 acc[8];
  #pragma unroll
  for (int t=0;t<8;t++) acc[t] = (f32x4){0.f,0.f,0.f,0.f};
  #pragma unroll
  for (int ks=0; ks<4; ks++){
    #pragma unroll
    for (int t=0;t<8;t++){
      int n0 = (ng*8 + t)*16;
      short8 bv = *(const short8*)(BWswz + ((size_t)(ks*4+quad)*NBU + n0 + ml)*8);
      acc[t] = __builtin_amdgcn_mfma_f32_16x16x32_bf16(av[ks], bv, acc[t], 0, 0, 0);
    }
  }
  #pragma unroll
  for (int t=0;t<8;t++){
    int n = (ng*8+t)*16 + ml;
    #pragma unroll
    for (int r=0;r<4;r++)
      sBu[lm0 + quad*4 + r][n] = f2bf(acc[t][r]);
  }
}

// ---- K1: per-chunk MFMA Bu -> LDS -> local scan -> chunk finals;
//          last block per group also does the 16-step group scan (in-place z + gfin) ----
__global__ __launch_bounds__(512) void bu_finals(const float* __restrict__ in,
                                                 const short* __restrict__ BWswz,
                                                 const float* __restrict__ A_diag,
                                                 const float* __restrict__ steps,
                                                 float* finals,
                                                 float* __restrict__ gfin,
                                                 unsigned* __restrict__ cnt){
  __shared__ unsigned short sBu[CL][NBU+8];    // 33.3 KB
  __shared__ int lastFlag;
  int c = blockIdx.x;
  chunk_bu_to_lds(c, in, BWswz, sBu);
  __syncthreads();
  int tid = threadIdx.x;
  int p = tid & 255, part = tid >> 8;
  Params q = get_params(A_diag, steps, p);
  float x1=0.f, x2=0.f;
  #pragma unroll
  for (int i=0;i<CL;i++){
    float u = bf2f(sBu[i][part*256 + p]);
    float n1 = q.M11*x1 + q.M12*x2 + q.s1*u;
    float n2 = q.M21*x1 + q.M22*x2 + q.s2*u;
    x1 = n1; x2 = n2;
  }
  ((float2*)finals)[(size_t)(part*NCH + c)*P + p] = make_float2(x1,x2);

  // completion counter: last block of the group performs the group scan
  __threadfence();                             // release our finals (device scope)
  if (tid == 0)
    lastFlag = (atomicAdd(&cnt[c >> 4], 1u) == GS - 1u);
  __syncthreads();
  if (lastFlag){
    __threadfence();                           // acquire: see all group finals
    int g = c >> 4;
    float a=q.M11, b=q.M12, cc=q.M21, d=q.M22;
    #pragma unroll
    for (int s=0;s<5;s++){                     // T = M^32
      float na=a*a+b*cc, nb=a*b+b*d, nc=cc*a+d*cc, nd=cc*b+d*d;
      a=na;b=nb;cc=nc;d=nd;
    }
    float2* z2 = (float2*)finals;
    float y1=0.f, y2=0.f;
    #pragma unroll
    for (int i=0;i<GS;i++){
      size_t idx = (size_t)(part*NCH + g*GS + i)*P + p;
      float2 f = z2[idx];
      z2[idx] = make_float2(y1,y2);            // group-local carry z
      float n1 = a*y1 + b*y2 + f.x;
      float n2 = cc*y1 + d*y2 + f.y;
      y1=n1; y2=n2;
    }
    ((float2*)gfin)[(size_t)(part*NG + g)*P + p] = make_float2(y1,y2);
  }
}

// ---- K2: fused final — MFMA Bu -> LDS; on-the-fly Y_g; scan w/ carry
//          (in-place x2 over LDS); out = x2 @ Bswz + in*D via MFMA ------------
__global__ __launch_bounds__(512) void fused_out(const float* __restrict__ in,
                                                 const short* __restrict__ BWswz,
                                                 const short* __restrict__ Bswz,
                                                 const float* __restrict__ A_diag,
                                                 const float* __restrict__ steps,
                                                 const float* __restrict__ zloc,
                                                 const float* __restrict__ gfin,
                                                 const float* __restrict__ Dv,
                                                 float* __restrict__ out){
  __shared__ unsigned short sX[CL][KDIM+8];    // Bu, overwritten in place by x2
  int c = blockIdx.x;
  chunk_bu_to_lds(c, in, BWswz, sX);
  __syncthreads();

  int tid = threadIdx.x;
  {
    int p = tid & 255, part = tid >> 8;
    int g = c >> 4, iw = c & (GS-1);
    Params q = get_params(A_diag, steps, p);
    // T = M^32
    float a=q.M11, b=q.M12, cc=q.M21, dd=q.M22;
    #pragma unroll
    for (int s=0;s<5;s++){
      float na=a*a+b*cc, nb=a*b+b*dd, nc=cc*a+dd*cc, nd=cc*b+dd*dd;
      a=na;b=nb;cc=nc;dd=nd;
    }
    // S = T^iw (iw wave-uniform)
    float sa=1.f, sb=0.f, sc=0.f, sd=1.f;
    {
      float wa=a, wb=b, wc=cc, wd=dd;
      #pragma unroll
      for (int bit=0; bit<4; bit++){
        if ((iw>>bit)&1){
          float na = wa*sa + wb*sc, nb = wa*sb + wb*sd;
          float nc = wc*sa + wd*sc, nd = wc*sb + wd*sd;
          sa=na; sb=nb; sc=nc; sd=nd;
        }
        float qa = wa*wa + wb*wc, qb = wa*wb + wb*wd;
        float qc = wc*wa + wd*wc, qd = wc*wb + wd*wd;
        wa=qa; wb=qb; wc=qc; wd=qd;
      }
    }
    // T_G = M^512 = T^16 (4 more squarings)
    float ga=a, gb=b, gc=cc, gd=dd;
    #pragma unroll
    for (int s=0;s<4;s++){
      float na=ga*ga+gb*gc, nb=ga*gb+gb*gd, nc=gc*ga+gd*gc, nd=gc*gb+gd*gd;
      ga=na;gb=nb;gc=nc;gd=nd;
    }
    // Y_g = sequential combine over gfin[0..g-1] (g wave-uniform, <=31 iters, L2-hit)
    float y1=0.f, y2=0.f;
    const float2* Z2 = (const float2*)gfin;
    for (int j=0; j<g; j++){
      float2 z = Z2[(size_t)(part*NG + j)*P + p];
      float n1 = ga*y1 + gb*y2 + z.x;
      float n2 = gc*y1 + gd*y2 + z.y;
      y1=n1; y2=n2;
    }
    float2 zc = ((const float2*)zloc)[(size_t)(part*NCH + c)*P + p];
    float x1 = sa*y1 + sb*y2 + zc.x;
    float x2 = sc*y1 + sd*y2 + zc.y;
    #pragma unroll
    for (int i=0;i<CL;i++){
      float u = bf2f(sX[i][part*256 + p]);
      float n1 = q.M11*x1 + q.M12*x2 + q.s1*u;
      float n2 = q.M21*x1 + q.M22*x2 + q.s2*u;
      x1 = n1; x2 = n2;
      sX[i][part*256 + p] = f2bf(x2);
    }
  }
  __syncthreads();

  // out GEMM: 32 rows x 128 h, A from LDS, 2 n-tiles per wave
  int lane = tid & 63, w = tid >> 6;
  int ml = lane & 15, quad = lane >> 4;
  int mt = w & 1;
  int ntb = (w >> 1) * 2;
  f32x4 acc[2];
  acc[0] = (f32x4){0.f,0.f,0.f,0.f};
  acc[1] = (f32x4){0.f,0.f,0.f,0.f};
  for (int ks=0; ks<KDIM/32; ks++){
    short8 av = *(const short8*)&sX[mt*16 + ml][ks*32 + quad*8];
    #pragma unroll
    for (int j=0;j<2;j++){
      short8 bv = *(const short8*)(Bswz + ((size_t)(ks*4+quad)*H + (ntb+j)*16 + ml)*8);
      acc[j] = __builtin_amdgcn_mfma_f32_16x16x32_bf16(av, bv, acc[j], 0, 0, 0);
    }
  }
  #pragma unroll
  for (int j=0;j<2;j++){
    int h = (ntb+j)*16 + ml;
    float dv = Dv[h];
    #pragma unroll
    for (int r=0;r<4;r++){
      int l = c*CL + mt*16 + quad*4 + r;
      out[(size_t)l*H + h] = acc[j][r] + in[(size_t)l*H + h]*dv;
    }
  }
}

extern "C" void kernel_launch(void* const* d_in, const int* in_sizes, int n_in,
                              void* d_out, int out_size, void* d_ws, size_t ws_size,
                              hipStream_t stream) {
  const float* in     = (const float*)d_in[0];   // (L,H)
  const float* A_diag = (const float*)d_in[1];   // (P,)
  const float* B      = (const float*)d_in[2];   // (P,H,2)
  const float* Cw     = (const float*)d_in[3];   // (H,P,2)
  const float* Dv     = (const float*)d_in[4];   // (H,)
  const float* steps  = (const float*)d_in[5];   // (P,)
  float* out = (float*)d_out;

  unsigned short* BWswz = (unsigned short*)d_ws;             // 128*512 bf16 (128KB)
  unsigned short* Bswz  = BWswz + (size_t)H*NBU;             // 512*128 bf16 (128KB)
  float* finals = (float*)(Bswz + (size_t)KDIM*H);           // 2*NCH*P*2 (2MB) -> zloc
  float* gfin   = finals + (size_t)2*NCH*P*2;                // 2*NG*P*2 (128KB)
  unsigned* cnt = (unsigned*)(gfin + (size_t)2*NG*P*2);      // NG counters

  prep_w<<<256, 512, 0, stream>>>(B, Cw, BWswz, Bswz, cnt);
  bu_finals<<<NCH, 512, 0, stream>>>(in, (const short*)BWswz, A_diag, steps,
                                     finals, gfin, cnt);
  fused_out<<<NCH, 512, 0, stream>>>(in, (const short*)BWswz, (const short*)Bswz,
                                     A_diag, steps, finals, gfin, Dv, out);
}

// Round 13
// 104.619 us; speedup vs baseline: 1.9452x; 1.9452x over previous
//
#include <hip/hip_runtime.h>
#include <math.h>

#define L 16384
#define H 128
#define P 256
#define CL 32
#define NCH (L/CL)   // 512 chunks
#define GS 16        // chunks per group
#define NG (NCH/GS)  // 32 groups
#define KDIM 512     // out-GEMM K = [x2re | x2im]
#define NBU 512      // bu-GEMM N  = [BuRe | BuIm]

typedef __attribute__((ext_vector_type(8))) short short8;   // 8 bf16
typedef __attribute__((ext_vector_type(4))) float f32x4;

__device__ inline unsigned short f2bf(float f){          // fp32 -> bf16 RNE
  union { float f; unsigned u; } v; v.f = f;
  unsigned u = v.u;
  u += 0x7fffu + ((u >> 16) & 1u);
  return (unsigned short)(u >> 16);
}
__device__ inline float bf2f(unsigned short s){
  union { unsigned u; float f; } v; v.u = ((unsigned)s) << 16;
  return v.f;
}

struct Params { float M11,M12,M21,M22,s1,s2; };

__device__ inline Params get_params(const float* A_diag, const float* steps, int p){
  float A = A_diag[p]; A = A > 0.f ? A : 0.f;          // relu
  float dt = 1.f/(1.f + expf(-steps[p]));              // sigmoid
  float schur = 1.f/(1.f + dt*dt*A);
  Params q;
  q.M11 = 1.f - dt*dt*A*schur;
  q.M12 = -dt*A*schur;
  q.M21 = dt*schur;
  q.M22 = schur;
  q.s1 = q.M11*dt;
  q.s2 = q.M21*dt;
  return q;
}

// ---- K0: prep — weight swizzles only (bf16). 256 blocks x 512 = 131072 thr:
// gid < 65536 -> BW swizzle; else -> C swizzle. NO fences, NO counters.
__global__ __launch_bounds__(512) void prep_w(const float* __restrict__ B,
                                              const float* __restrict__ Cw,
                                              unsigned short* __restrict__ BWswz,
                                              unsigned short* __restrict__ Bswz){
  int gid = blockIdx.x*512 + threadIdx.x;
  if (gid < H*NBU){                            // BW: k=h 0..127, n 0..511
    int k = gid >> 9, n = gid & 511;
    int p = n & 255, c2 = n >> 8;
    float v = B[((size_t)p*H + k)*2 + c2];
    BWswz[((size_t)(k>>3)*NBU + n)*8 + (k&7)] = f2bf(v);
  } else {
    int g2 = gid - H*NBU;                      // C: k 0..511, n=h 0..127
    int k = g2 >> 7, n = g2 & 127;
    float v = (k < P) ? Cw[((size_t)n*P + k)*2]
                      : -Cw[((size_t)n*P + (k-P))*2 + 1];
    Bswz[((size_t)(k>>3)*H + n)*8 + (k&7)] = f2bf(v);
  }
}

// ---- shared helper: MFMA one chunk of Bu into LDS (bf16), A direct from fp32 in ----
__device__ inline void chunk_bu_to_lds(int c, const float* __restrict__ in,
                                       const short* __restrict__ BWswz,
                                       unsigned short (*sBu)[NBU+8]){
  int tid = threadIdx.x;
  int lane = tid & 63, w = tid >> 6;
  int ml = lane & 15, quad = lane >> 4;
  int mt = w & 1, ng = w >> 1;
  int lm0 = mt*16;
  const float* aptr = in + (size_t)(c*CL + lm0 + ml)*H + quad*8;
  short8 av[4];
  #pragma unroll
  for (int ks=0; ks<4; ks++){
    float4 f0 = *(const float4*)(aptr + ks*32);
    float4 f1 = *(const float4*)(aptr + ks*32 + 4);
    union { short8 s; unsigned short u[8]; } o;
    o.u[0]=f2bf(f0.x); o.u[1]=f2bf(f0.y); o.u[2]=f2bf(f0.z); o.u[3]=f2bf(f0.w);
    o.u[4]=f2bf(f1.x); o.u[5]=f2bf(f1.y); o.u[6]=f2bf(f1.z); o.u[7]=f2bf(f1.w);
    av[ks] = o.s;
  }
  f32x4 acc[8];
  #pragma unroll
  for (int t=0;t<8;t++) acc[t] = (f32x4){0.f,0.f,0.f,0.f};
  #pragma unroll
  for (int ks=0; ks<4; ks++){
    #pragma unroll
    for (int t=0;t<8;t++){
      int n0 = (ng*8 + t)*16;
      short8 bv = *(const short8*)(BWswz + ((size_t)(ks*4+quad)*NBU + n0 + ml)*8);
      acc[t] = __builtin_amdgcn_mfma_f32_16x16x32_bf16(av[ks], bv, acc[t], 0, 0, 0);
    }
  }
  #pragma unroll
  for (int t=0;t<8;t++){
    int n = (ng*8+t)*16 + ml;
    #pragma unroll
    for (int r=0;r<4;r++)
      sBu[lm0 + quad*4 + r][n] = f2bf(acc[t][r]);
  }
}

// ---- K1: per-chunk MFMA Bu -> LDS -> local scan -> chunk finals (no fences) ----
__global__ __launch_bounds__(512) void bu_finals(const float* __restrict__ in,
                                                 const short* __restrict__ BWswz,
                                                 const float* __restrict__ A_diag,
                                                 const float* __restrict__ steps,
                                                 float* __restrict__ finals){
  __shared__ unsigned short sBu[CL][NBU+8];    // 33.3 KB
  int c = blockIdx.x;
  chunk_bu_to_lds(c, in, BWswz, sBu);
  __syncthreads();
  int tid = threadIdx.x;
  int p = tid & 255, part = tid >> 8;
  Params q = get_params(A_diag, steps, p);
  float x1=0.f, x2=0.f;
  #pragma unroll
  for (int i=0;i<CL;i++){
    float u = bf2f(sBu[i][part*256 + p]);
    float n1 = q.M11*x1 + q.M12*x2 + q.s1*u;
    float n2 = q.M21*x1 + q.M22*x2 + q.s2*u;
    x1 = n1; x2 = n2;
  }
  ((float2*)finals)[(size_t)(part*NCH + c)*P + p] = make_float2(x1,x2);
}

// ---- K2: per-group local scan of chunk finals (in place -> z), group final -> gfin ----
__global__ __launch_bounds__(512) void group_scan(const float* __restrict__ A_diag,
                                                  const float* __restrict__ steps,
                                                  float* zf,
                                                  float* __restrict__ gfin){
  int tid = threadIdx.x;
  int p = tid & (P-1);
  int part = tid >> 8;
  int g = blockIdx.x;
  Params q = get_params(A_diag, steps, p);
  float a=q.M11, b=q.M12, c=q.M21, d=q.M22;
  #pragma unroll
  for (int s=0;s<5;s++){            // T = M^32
    float na=a*a+b*c, nb=a*b+b*d, nc=c*a+d*c, nd=c*b+d*d;
    a=na;b=nb;c=nc;d=nd;
  }
  float2* z2 = (float2*)zf;
  float x1=0.f, x2=0.f;
  #pragma unroll
  for (int i=0;i<GS;i++){
    size_t idx = (size_t)(part*NCH + g*GS + i)*P + p;
    float2 f = z2[idx];
    z2[idx] = make_float2(x1,x2);
    float n1 = a*x1 + b*x2 + f.x;
    float n2 = c*x1 + d*x2 + f.y;
    x1=n1; x2=n2;
  }
  ((float2*)gfin)[(size_t)(part*NG + g)*P + p] = make_float2(x1,x2);
}

// ---- K3: fused final — MFMA Bu -> LDS; on-the-fly Y_g; scan w/ carry
//          (in-place x2 over LDS); out = x2 @ Bswz + in*D via MFMA ------------
__global__ __launch_bounds__(512) void fused_out(const float* __restrict__ in,
                                                 const short* __restrict__ BWswz,
                                                 const short* __restrict__ Bswz,
                                                 const float* __restrict__ A_diag,
                                                 const float* __restrict__ steps,
                                                 const float* __restrict__ zloc,
                                                 const float* __restrict__ gfin,
                                                 const float* __restrict__ Dv,
                                                 float* __restrict__ out){
  __shared__ unsigned short sX[CL][KDIM+8];    // Bu, overwritten in place by x2
  int c = blockIdx.x;
  chunk_bu_to_lds(c, in, BWswz, sX);
  __syncthreads();

  int tid = threadIdx.x;
  {
    int p = tid & 255, part = tid >> 8;
    int g = c >> 4, iw = c & (GS-1);
    Params q = get_params(A_diag, steps, p);
    // T = M^32
    float a=q.M11, b=q.M12, cc=q.M21, dd=q.M22;
    #pragma unroll
    for (int s=0;s<5;s++){
      float na=a*a+b*cc, nb=a*b+b*dd, nc=cc*a+dd*cc, nd=cc*b+dd*dd;
      a=na;b=nb;cc=nc;dd=nd;
    }
    // S = T^iw (iw wave-uniform)
    float sa=1.f, sb=0.f, sc=0.f, sd=1.f;
    {
      float wa=a, wb=b, wc=cc, wd=dd;
      #pragma unroll
      for (int bit=0; bit<4; bit++){
        if ((iw>>bit)&1){
          float na = wa*sa + wb*sc, nb = wa*sb + wb*sd;
          float nc = wc*sa + wd*sc, nd = wc*sb + wd*sd;
          sa=na; sb=nb; sc=nc; sd=nd;
        }
        float qa = wa*wa + wb*wc, qb = wa*wb + wb*wd;
        float qc = wc*wa + wd*wc, qd = wc*wb + wd*wd;
        wa=qa; wb=qb; wc=qc; wd=qd;
      }
    }
    // T_G = M^512 = T^16 (4 more squarings)
    float ga=a, gb=b, gc=cc, gd=dd;
    #pragma unroll
    for (int s=0;s<4;s++){
      float na=ga*ga+gb*gc, nb=ga*gb+gb*gd, nc=gc*ga+gd*gc, nd=gc*gb+gd*gd;
      ga=na;gb=nb;gc=nc;gd=nd;
    }
    // Y_g = sequential combine over gfin[0..g-1] (g wave-uniform, <=31 iters, L2-hit)
    float y1=0.f, y2=0.f;
    const float2* Z2 = (const float2*)gfin;
    for (int j=0; j<g; j++){
      float2 z = Z2[(size_t)(part*NG + j)*P + p];
      float n1 = ga*y1 + gb*y2 + z.x;
      float n2 = gc*y1 + gd*y2 + z.y;
      y1=n1; y2=n2;
    }
    float2 zc = ((const float2*)zloc)[(size_t)(part*NCH + c)*P + p];
    float x1 = sa*y1 + sb*y2 + zc.x;
    float x2 = sc*y1 + sd*y2 + zc.y;
    #pragma unroll
    for (int i=0;i<CL;i++){
      float u = bf2f(sX[i][part*256 + p]);
      float n1 = q.M11*x1 + q.M12*x2 + q.s1*u;
      float n2 = q.M21*x1 + q.M22*x2 + q.s2*u;
      x1 = n1; x2 = n2;
      sX[i][part*256 + p] = f2bf(x2);
    }
  }
  __syncthreads();

  // out GEMM: 32 rows x 128 h, A from LDS, 2 n-tiles per wave
  int lane = tid & 63, w = tid >> 6;
  int ml = lane & 15, quad = lane >> 4;
  int mt = w & 1;
  int ntb = (w >> 1) * 2;
  f32x4 acc[2];
  acc[0] = (f32x4){0.f,0.f,0.f,0.f};
  acc[1] = (f32x4){0.f,0.f,0.f,0.f};
  for (int ks=0; ks<KDIM/32; ks++){
    short8 av = *(const short8*)&sX[mt*16 + ml][ks*32 + quad*8];
    #pragma unroll
    for (int j=0;j<2;j++){
      short8 bv = *(const short8*)(Bswz + ((size_t)(ks*4+quad)*H + (ntb+j)*16 + ml)*8);
      acc[j] = __builtin_amdgcn_mfma_f32_16x16x32_bf16(av, bv, acc[j], 0, 0, 0);
    }
  }
  #pragma unroll
  for (int j=0;j<2;j++){
    int h = (ntb+j)*16 + ml;
    float dv = Dv[h];
    #pragma unroll
    for (int r=0;r<4;r++){
      int l = c*CL + mt*16 + quad*4 + r;
      out[(size_t)l*H + h] = acc[j][r] + in[(size_t)l*H + h]*dv;
    }
  }
}

extern "C" void kernel_launch(void* const* d_in, const int* in_sizes, int n_in,
                              void* d_out, int out_size, void* d_ws, size_t ws_size,
                              hipStream_t stream) {
  const float* in     = (const float*)d_in[0];   // (L,H)
  const float* A_diag = (const float*)d_in[1];   // (P,)
  const float* B      = (const float*)d_in[2];   // (P,H,2)
  const float* Cw     = (const float*)d_in[3];   // (H,P,2)
  const float* Dv     = (const float*)d_in[4];   // (H,)
  const float* steps  = (const float*)d_in[5];   // (P,)
  float* out = (float*)d_out;

  unsigned short* BWswz = (unsigned short*)d_ws;             // 128*512 bf16 (128KB)
  unsigned short* Bswz  = BWswz + (size_t)H*NBU;             // 512*128 bf16 (128KB)
  float* finals = (float*)(Bswz + (size_t)KDIM*H);           // 2*NCH*P*2 (2MB) -> zloc
  float* gfin   = finals + (size_t)2*NCH*P*2;                // 2*NG*P*2 (128KB)

  prep_w<<<256, 512, 0, stream>>>(B, Cw, BWswz, Bswz);
  bu_finals<<<NCH, 512, 0, stream>>>(in, (const short*)BWswz, A_diag, steps, finals);
  group_scan<<<NG, 512, 0, stream>>>(A_diag, steps, finals, gfin);
  fused_out<<<NCH, 512, 0, stream>>>(in, (const short*)BWswz, (const short*)Bswz,
                                     A_diag, steps, finals, gfin, Dv, out);
}